// Round 1
// baseline (409.799 us; speedup 1.0000x reference)
//
#include <hip/hip_runtime.h>

#define SS 2048
#define DD 128
#define NB 16
#define TM 128
#define TN 64
#define NITER (SS / TN)
#define SCALE 0.08838834764831845f

typedef short bf16x8 __attribute__((ext_vector_type(8)));
typedef float f32x4 __attribute__((ext_vector_type(4)));

#define KSTRIDE 136   // 128 + 8 pad, bf16 elements (272 B rows -> 2-way max on frag reads)
#define VSTRIDE 72    // 64 + 8 pad
#define PSTRIDE 72

__device__ __forceinline__ unsigned short f2bf(float x) {
    unsigned u = __builtin_bit_cast(unsigned, x);
    u += 0x7fffu + ((u >> 16) & 1u);          // RNE
    return (unsigned short)(u >> 16);
}
__device__ __forceinline__ float bf2f(unsigned short h) {
    unsigned u = ((unsigned)h) << 16;
    return __builtin_bit_cast(float, u);
}

// ---- pre-kernel 1: fp32 -> bf16 for Q and K ----
__global__ void cvt_qk_kernel(const float* __restrict__ q, const float* __restrict__ k,
                              unsigned short* __restrict__ qb, unsigned short* __restrict__ kb) {
    int i = (blockIdx.x * 256 + threadIdx.x) * 4;
    float4 a = *(const float4*)(q + i);
    float4 b = *(const float4*)(k + i);
    ushort4 ua; ua.x = f2bf(a.x); ua.y = f2bf(a.y); ua.z = f2bf(a.z); ua.w = f2bf(a.w);
    ushort4 ub; ub.x = f2bf(b.x); ub.y = f2bf(b.y); ub.z = f2bf(b.z); ub.w = f2bf(b.w);
    *(ushort4*)(qb + i) = ua;
    *(ushort4*)(kb + i) = ub;
}

// ---- pre-kernel 2: V [B][S][D] fp32 -> Vt [B][D][S] bf16 ----
__global__ void tr_v_kernel(const float* __restrict__ v, unsigned short* __restrict__ vt) {
    __shared__ unsigned short t[64 * 72];
    int b = blockIdx.z, sb = blockIdx.y * 64, db = blockIdx.x * 64;
    int tid = threadIdx.x;
    int r16 = tid >> 4, c4 = (tid & 15) * 4;
    for (int i = 0; i < 4; ++i) {
        int sl = i * 16 + r16;
        float4 x = *(const float4*)(v + ((size_t)(b * SS + sb + sl) * DD + db + c4));
        ushort4 u; u.x = f2bf(x.x); u.y = f2bf(x.y); u.z = f2bf(x.z); u.w = f2bf(x.w);
        *(ushort4*)&t[sl * 72 + c4] = u;
    }
    __syncthreads();
    for (int i = 0; i < 4; ++i) {
        int dl = i * 16 + r16;
        ushort4 u;
        u.x = t[(c4 + 0) * 72 + dl];
        u.y = t[(c4 + 1) * 72 + dl];
        u.z = t[(c4 + 2) * 72 + dl];
        u.w = t[(c4 + 3) * 72 + dl];
        *(ushort4*)(vt + ((size_t)(b * DD + db + dl) * SS + sb + c4)) = u;
    }
}

// ---- main fused attention kernel: one 128-row Q-tile per workgroup ----
__global__ __launch_bounds__(512, 2)
void attn_kernel(const unsigned short* __restrict__ qb,
                 const unsigned short* __restrict__ kb,
                 const unsigned short* __restrict__ vt,
                 float* __restrict__ attn, float* __restrict__ ctx) {
    __shared__ unsigned short K_lds[TN * KSTRIDE];   // 17408 B
    __shared__ unsigned short V_lds[DD * VSTRIDE];   // 18432 B  (V^T tile: [d][k])
    __shared__ unsigned short P_lds[TM * PSTRIDE];   // 18432 B
    __shared__ float rs_lds[TM];
    __shared__ float inv_lds[TM];

    const int tid = threadIdx.x;
    const int lane = tid & 63, w = tid >> 6;
    const int wm = w >> 2, wn = w & 3;               // waves: 2 (rows) x 4 (cols)
    const int l15 = lane & 15, quad = lane >> 4;
    const int bb = blockIdx.y;
    const int q0 = blockIdx.x * TM;

    if (tid < TM) rs_lds[tid] = 0.0f;

    // Q fragments in registers: rows wm*64..+64, all of D. A-layout: m=l15, k=quad*8+j
    bf16x8 qf[4][4];
    {
        const unsigned short* qg = qb + ((size_t)(bb * SS + q0 + wm * 64 + l15)) * DD + quad * 8;
        for (int mi = 0; mi < 4; ++mi)
            for (int kk = 0; kk < 4; ++kk)
                qf[mi][kk] = *(const bf16x8*)(qg + mi * 16 * DD + kk * 32);
    }

    const unsigned short* kgb = kb + (size_t)bb * SS * DD;
    const unsigned short* vgb = vt + (size_t)bb * DD * SS;

    // ================= phase A: rowsums of exp(scale * Q K^T) =================
    float rs[16];
    for (int j = 0; j < 16; ++j) rs[j] = 0.0f;

    for (int it = 0; it < NITER; ++it) {
        const int k0 = it * TN;
        __syncthreads();
        {   // stage K tile (bf16, 64 keys x 128 d)
            const unsigned short* kg = kgb + (size_t)k0 * DD;
            for (int c = 0; c < 2; ++c) {
                int e = c * 4096 + tid * 8;
                *(bf16x8*)&K_lds[(e >> 7) * KSTRIDE + (e & 127)] = *(const bf16x8*)(kg + e);
            }
        }
        __syncthreads();
        f32x4 acc[4];
        for (int mi = 0; mi < 4; ++mi) acc[mi] = (f32x4){0.f, 0.f, 0.f, 0.f};
        for (int kk = 0; kk < 4; ++kk) {
            bf16x8 bf = *(const bf16x8*)&K_lds[(wn * 16 + l15) * KSTRIDE + kk * 32 + quad * 8];
            for (int mi = 0; mi < 4; ++mi)
                acc[mi] = __builtin_amdgcn_mfma_f32_16x16x32_bf16(qf[mi][kk], bf, acc[mi], 0, 0, 0);
        }
        for (int mi = 0; mi < 4; ++mi)
            for (int r = 0; r < 4; ++r)
                rs[mi * 4 + r] += __expf(acc[mi][r] * SCALE);
    }

    // reduce across the 16 column-lanes sharing each row
    for (int j = 0; j < 16; ++j) {
        float v = rs[j];
        v += __shfl_xor(v, 1, 64);
        v += __shfl_xor(v, 2, 64);
        v += __shfl_xor(v, 4, 64);
        v += __shfl_xor(v, 8, 64);
        rs[j] = v;
    }
    if (l15 == 0)
        for (int mi = 0; mi < 4; ++mi)
            for (int r = 0; r < 4; ++r)
                atomicAdd(&rs_lds[wm * 64 + mi * 16 + quad * 4 + r], rs[mi * 4 + r]);
    __syncthreads();
    if (tid < TM) inv_lds[tid] = 1.0f / rs_lds[tid];
    __syncthreads();
    float inv[16];
    for (int mi = 0; mi < 4; ++mi)
        for (int r = 0; r < 4; ++r)
            inv[mi * 4 + r] = inv_lds[wm * 64 + mi * 16 + quad * 4 + r];

    // ================= phase B: P = E/rowsum -> global, and C += P V =================
    f32x4 cacc[4][2];
    for (int mi = 0; mi < 4; ++mi)
        for (int ni = 0; ni < 2; ++ni) cacc[mi][ni] = (f32x4){0.f, 0.f, 0.f, 0.f};

    float* ag = attn + (size_t)bb * SS * SS + (size_t)q0 * SS;

    for (int it = 0; it < NITER; ++it) {
        const int k0 = it * TN;
        __syncthreads();
        {   // stage K tile
            const unsigned short* kg = kgb + (size_t)k0 * DD;
            for (int c = 0; c < 2; ++c) {
                int e = c * 4096 + tid * 8;
                *(bf16x8*)&K_lds[(e >> 7) * KSTRIDE + (e & 127)] = *(const bf16x8*)(kg + e);
            }
        }
        {   // stage Vt tile: [d=128][k=64] from Vt global rows (contiguous)
            const unsigned short* vg = vgb + k0;
            for (int c = 0; c < 2; ++c) {
                int e = c * 4096 + tid * 8;
                int dr = e >> 6, ck = e & 63;
                *(bf16x8*)&V_lds[dr * VSTRIDE + ck] = *(const bf16x8*)(vg + (size_t)dr * SS + ck);
            }
        }
        __syncthreads();

        f32x4 acc[4];
        for (int mi = 0; mi < 4; ++mi) acc[mi] = (f32x4){0.f, 0.f, 0.f, 0.f};
        for (int kk = 0; kk < 4; ++kk) {
            bf16x8 bf = *(const bf16x8*)&K_lds[(wn * 16 + l15) * KSTRIDE + kk * 32 + quad * 8];
            for (int mi = 0; mi < 4; ++mi)
                acc[mi] = __builtin_amdgcn_mfma_f32_16x16x32_bf16(qf[mi][kk], bf, acc[mi], 0, 0, 0);
        }
        // normalized probabilities -> P_lds (bf16)
        for (int mi = 0; mi < 4; ++mi)
            for (int r = 0; r < 4; ++r) {
                float p = __expf(acc[mi][r] * SCALE) * inv[mi * 4 + r];
                P_lds[(wm * 64 + mi * 16 + quad * 4 + r) * PSTRIDE + wn * 16 + l15] = f2bf(p);
            }
        __syncthreads();

        // PV: C[128 x 128] over 8 waves (wm rows, w&3 -> 32 d-cols each)
        for (int kk = 0; kk < 2; ++kk) {
            bf16x8 af[4];
            for (int mi = 0; mi < 4; ++mi)
                af[mi] = *(const bf16x8*)&P_lds[(wm * 64 + mi * 16 + l15) * PSTRIDE + kk * 32 + quad * 8];
            for (int ni = 0; ni < 2; ++ni) {
                bf16x8 bf = *(const bf16x8*)&V_lds[((w & 3) * 32 + ni * 16 + l15) * VSTRIDE + kk * 32 + quad * 8];
                for (int mi = 0; mi < 4; ++mi)
                    cacc[mi][ni] = __builtin_amdgcn_mfma_f32_16x16x32_bf16(af[mi], bf, cacc[mi][ni], 0, 0, 0);
            }
        }

        // coalesced P store to global attention (fp32, 256B row segments)
        for (int c = 0; c < 4; ++c) {
            int e = c * 2048 + tid * 4;
            int row = e >> 6, col = e & 63;
            const unsigned short* ps = &P_lds[row * PSTRIDE + col];
            float4 o;
            o.x = bf2f(ps[0]); o.y = bf2f(ps[1]); o.z = bf2f(ps[2]); o.w = bf2f(ps[3]);
            *(float4*)(ag + (size_t)row * SS + k0 + col) = o;
        }
    }

    // epilogue: context store (already normalized since P was normalized)
    float* cg = ctx + ((size_t)(bb * SS) + q0) * DD;
    for (int mi = 0; mi < 4; ++mi)
        for (int ni = 0; ni < 2; ++ni)
            for (int r = 0; r < 4; ++r) {
                int row = wm * 64 + mi * 16 + quad * 4 + r;
                int col = (w & 3) * 32 + ni * 16 + l15;
                cg[(size_t)row * DD + col] = cacc[mi][ni][r];
            }
}

extern "C" void kernel_launch(void* const* d_in, const int* in_sizes, int n_in,
                              void* d_out, int out_size, void* d_ws, size_t ws_size,
                              hipStream_t stream) {
    const float* q = (const float*)d_in[0];
    const float* k = (const float*)d_in[1];
    const float* v = (const float*)d_in[2];
    float* ctx = (float*)d_out;
    float* attn = ctx + (size_t)NB * SS * DD;

    unsigned short* qb = (unsigned short*)d_ws;            // B*S*D bf16
    unsigned short* kb = qb + (size_t)NB * SS * DD;
    unsigned short* vt = kb + (size_t)NB * SS * DD;        // [B][D][S] bf16

    cvt_qk_kernel<<<dim3((NB * SS * DD) / (256 * 4)), 256, 0, stream>>>(q, k, qb, kb);
    tr_v_kernel<<<dim3(DD / 64, SS / 64, NB), 256, 0, stream>>>(v, vt);
    attn_kernel<<<dim3(SS / TM, NB), 512, 0, stream>>>(qb, kb, vt, attn, ctx);
}

// Round 2
// 371.750 us; speedup vs baseline: 1.1024x; 1.1024x over previous
//
#include <hip/hip_runtime.h>

#define SS 2048
#define DD 128
#define NB 16
#define TM 64
#define TN 64
#define NITER (SS / TN)

typedef short bf16x8 __attribute__((ext_vector_type(8)));
typedef float f32x4 __attribute__((ext_vector_type(4)));

#define KSTRIDE 136   // 128 + 8 pad (bf16 elems)
#define VSTRIDE 72    // 64 + 8 pad
#define PSTRIDE 72

// scale * log2(e): softmax base-2 trick (exp2 consistently in num+denom == softmax)
#define SL2E (0.08838834764831845f * 1.4426950408889634f)

__device__ __forceinline__ unsigned short f2bf(float x) {
    unsigned u = __builtin_bit_cast(unsigned, x);
    u += 0x7fffu + ((u >> 16) & 1u);          // RNE
    return (unsigned short)(u >> 16);
}

__device__ __forceinline__ float fexp2(float x) {
#if __has_builtin(__builtin_amdgcn_exp2f)
    return __builtin_amdgcn_exp2f(x);
#else
    return __expf(x * 0.6931471805599453f);
#endif
}

// ---- pre-kernel: K fp32->bf16 (x=2,3) and V [B][S][D] -> Vt [B][D][S] bf16 (x=0,1) ----
__global__ void prep_kernel(const float* __restrict__ k, const float* __restrict__ v,
                            unsigned short* __restrict__ kb, unsigned short* __restrict__ vt) {
    __shared__ unsigned short t[64 * 72];
    const int x = blockIdx.x, b = blockIdx.z, sb = blockIdx.y * 64;
    const int tid = threadIdx.x;
    if (x < 2) {
        const int db = x * 64;
        const int r16 = tid >> 4, c4 = (tid & 15) * 4;
        for (int i = 0; i < 4; ++i) {
            int sl = i * 16 + r16;
            float4 xx = *(const float4*)(v + ((size_t)(b * SS + sb + sl) * DD + db + c4));
            ushort4 u; u.x = f2bf(xx.x); u.y = f2bf(xx.y); u.z = f2bf(xx.z); u.w = f2bf(xx.w);
            *(ushort4*)&t[sl * 72 + c4] = u;
        }
        __syncthreads();
        for (int i = 0; i < 4; ++i) {
            int dl = i * 16 + r16;
            ushort4 u;
            u.x = t[(c4 + 0) * 72 + dl];
            u.y = t[(c4 + 1) * 72 + dl];
            u.z = t[(c4 + 2) * 72 + dl];
            u.w = t[(c4 + 3) * 72 + dl];
            *(ushort4*)(vt + ((size_t)(b * DD + db + dl) * SS + sb + c4)) = u;
        }
    } else {
        const int c0 = (x - 2) * 64;
        for (int i = 0; i < 4; ++i) {
            int e = i * 1024 + tid * 4;
            int r = e >> 6, c = e & 63;
            size_t off = (size_t)(b * SS + sb + r) * DD + c0 + c;
            float4 xx = *(const float4*)(k + off);
            ushort4 u; u.x = f2bf(xx.x); u.y = f2bf(xx.y); u.z = f2bf(xx.z); u.w = f2bf(xx.w);
            *(ushort4*)(kb + off) = u;
        }
    }
}

// ---- main fused attention: one 64-row Q-tile per WG, 2 blocks/CU ----
__global__ __launch_bounds__(512, 4)
void attn_kernel(const float* __restrict__ q,
                 const unsigned short* __restrict__ kb,
                 const unsigned short* __restrict__ vt,
                 float* __restrict__ attn, float* __restrict__ ctx) {
    __shared__ unsigned short K_lds[TN * KSTRIDE];   // 17408 B
    __shared__ unsigned short V_lds[DD * VSTRIDE];   // 18432 B
    __shared__ unsigned short P_lds[TM * PSTRIDE];   //  9216 B
    __shared__ float rs_lds[TM];
    __shared__ float inv_lds[TM];

    const int tid = threadIdx.x;
    const int lane = tid & 63, w = tid >> 6;
    const int wm = w >> 2, wn = w & 3;               // 2 row-waves x 4 col-waves
    const int l15 = lane & 15, quad = lane >> 4;

    // XCD-batch swizzle: blocks on XCD x (bid%8) handle batches {2x, 2x+1}
    // so each XCD's 4 MiB L2 holds only ~2 MB of K/V bf16 (heuristic; safe).
    const int bid = blockIdx.x;
    const int bb = ((bid & 7) << 1) | ((bid >> 3) & 1);
    const int q0 = (bid >> 4) * TM;

    if (tid < TM) rs_lds[tid] = 0.0f;

    // Q fragments from fp32 global, converted in registers. A-layout: m=l15, k=quad*8+j
    bf16x8 qf[2][4];
    {
        const float* qg = q + ((size_t)(bb * SS + q0 + wm * 32 + l15)) * DD + quad * 8;
        for (int mi = 0; mi < 2; ++mi)
            for (int kk = 0; kk < 4; ++kk) {
                float4 a = *(const float4*)(qg + mi * 16 * DD + kk * 32);
                float4 b = *(const float4*)(qg + mi * 16 * DD + kk * 32 + 4);
                bf16x8 f;
                f[0] = (short)f2bf(a.x); f[1] = (short)f2bf(a.y);
                f[2] = (short)f2bf(a.z); f[3] = (short)f2bf(a.w);
                f[4] = (short)f2bf(b.x); f[5] = (short)f2bf(b.y);
                f[6] = (short)f2bf(b.z); f[7] = (short)f2bf(b.w);
                qf[mi][kk] = f;
            }
    }

    const unsigned short* kgb = kb + (size_t)bb * SS * DD;
    const unsigned short* vgb = vt + (size_t)bb * DD * SS;

    // ================= phase A: rowsums of exp2(SL2E * Q K^T) =================
    float rs[8];
    for (int j = 0; j < 8; ++j) rs[j] = 0.0f;

    for (int it = 0; it < NITER; ++it) {
        __syncthreads();
        {
            const unsigned short* kg = kgb + (size_t)(it * TN) * DD;
            for (int c = 0; c < 2; ++c) {
                int e = c * 4096 + tid * 8;
                *(bf16x8*)&K_lds[(e >> 7) * KSTRIDE + (e & 127)] = *(const bf16x8*)(kg + e);
            }
        }
        __syncthreads();
        f32x4 acc[2];
        acc[0] = (f32x4){0.f, 0.f, 0.f, 0.f};
        acc[1] = (f32x4){0.f, 0.f, 0.f, 0.f};
        for (int kk = 0; kk < 4; ++kk) {
            bf16x8 bfv = *(const bf16x8*)&K_lds[(wn * 16 + l15) * KSTRIDE + kk * 32 + quad * 8];
            for (int mi = 0; mi < 2; ++mi)
                acc[mi] = __builtin_amdgcn_mfma_f32_16x16x32_bf16(qf[mi][kk], bfv, acc[mi], 0, 0, 0);
        }
        for (int mi = 0; mi < 2; ++mi)
            for (int r = 0; r < 4; ++r)
                rs[mi * 4 + r] += fexp2(acc[mi][r] * SL2E);
    }

    for (int j = 0; j < 8; ++j) {
        float s = rs[j];
        s += __shfl_xor(s, 1, 64);
        s += __shfl_xor(s, 2, 64);
        s += __shfl_xor(s, 4, 64);
        s += __shfl_xor(s, 8, 64);
        rs[j] = s;
    }
    if (l15 == 0)
        for (int mi = 0; mi < 2; ++mi)
            for (int r = 0; r < 4; ++r)
                atomicAdd(&rs_lds[wm * 32 + mi * 16 + quad * 4 + r], rs[mi * 4 + r]);
    __syncthreads();
    if (tid < TM) inv_lds[tid] = 1.0f / rs_lds[tid];
    __syncthreads();
    float inv[8];
    for (int mi = 0; mi < 2; ++mi)
        for (int r = 0; r < 4; ++r)
            inv[mi * 4 + r] = inv_lds[wm * 32 + mi * 16 + quad * 4 + r];

    // ================= phase B: P -> global (from regs) + C += P V =================
    f32x4 cacc[2][2];
    for (int mi = 0; mi < 2; ++mi)
        for (int ni = 0; ni < 2; ++ni) cacc[mi][ni] = (f32x4){0.f, 0.f, 0.f, 0.f};

    float* ap[8];
    for (int mi = 0; mi < 2; ++mi)
        for (int r = 0; r < 4; ++r)
            ap[mi * 4 + r] = attn + (size_t)bb * SS * SS
                           + (size_t)(q0 + wm * 32 + mi * 16 + quad * 4 + r) * SS
                           + wn * 16 + l15;

    for (int it = 0; it < NITER; ++it) {
        const int k0 = it * TN;
        __syncthreads();                       // prev-iter LDS readers done
        {
            const unsigned short* kg = kgb + (size_t)k0 * DD;
            for (int c = 0; c < 2; ++c) {
                int e = c * 4096 + tid * 8;
                *(bf16x8*)&K_lds[(e >> 7) * KSTRIDE + (e & 127)] = *(const bf16x8*)(kg + e);
            }
            const unsigned short* vg = vgb + k0;
            for (int c = 0; c < 2; ++c) {
                int e = c * 4096 + tid * 8;
                int dr = e >> 6, ck = e & 63;
                *(bf16x8*)&V_lds[dr * VSTRIDE + ck] = *(const bf16x8*)(vg + (size_t)dr * SS + ck);
            }
        }
        __syncthreads();

        f32x4 acc[2];
        acc[0] = (f32x4){0.f, 0.f, 0.f, 0.f};
        acc[1] = (f32x4){0.f, 0.f, 0.f, 0.f};
        for (int kk = 0; kk < 4; ++kk) {
            bf16x8 bfv = *(const bf16x8*)&K_lds[(wn * 16 + l15) * KSTRIDE + kk * 32 + quad * 8];
            for (int mi = 0; mi < 2; ++mi)
                acc[mi] = __builtin_amdgcn_mfma_f32_16x16x32_bf16(qf[mi][kk], bfv, acc[mi], 0, 0, 0);
        }

        // normalized P: fp32 direct to global (C-layout dword stores), bf16 to LDS for PV
        for (int mi = 0; mi < 2; ++mi)
            for (int r = 0; r < 4; ++r) {
                float p = fexp2(acc[mi][r] * SL2E) * inv[mi * 4 + r];
                ap[mi * 4 + r][0] = p;
                P_lds[(wm * 32 + mi * 16 + quad * 4 + r) * PSTRIDE + wn * 16 + l15] = f2bf(p);
            }
        for (int j = 0; j < 8; ++j) ap[j] += TN;
        __syncthreads();

        // PV: C[64 x 128] over 8 waves (wm: 32 rows, wn: 32 d-cols)
        for (int kk = 0; kk < 2; ++kk) {
            bf16x8 af[2];
            for (int mi = 0; mi < 2; ++mi)
                af[mi] = *(const bf16x8*)&P_lds[(wm * 32 + mi * 16 + l15) * PSTRIDE + kk * 32 + quad * 8];
            for (int ni = 0; ni < 2; ++ni) {
                bf16x8 bv = *(const bf16x8*)&V_lds[(wn * 32 + ni * 16 + l15) * VSTRIDE + kk * 32 + quad * 8];
                for (int mi = 0; mi < 2; ++mi)
                    cacc[mi][ni] = __builtin_amdgcn_mfma_f32_16x16x32_bf16(af[mi], bv, cacc[mi][ni], 0, 0, 0);
            }
        }
    }

    // epilogue: context
    float* cg = ctx + ((size_t)(bb * SS) + q0) * DD;
    for (int mi = 0; mi < 2; ++mi)
        for (int ni = 0; ni < 2; ++ni)
            for (int r = 0; r < 4; ++r) {
                int row = wm * 32 + mi * 16 + quad * 4 + r;
                int col = wn * 32 + ni * 16 + l15;
                cg[(size_t)row * DD + col] = cacc[mi][ni][r];
            }
}

extern "C" void kernel_launch(void* const* d_in, const int* in_sizes, int n_in,
                              void* d_out, int out_size, void* d_ws, size_t ws_size,
                              hipStream_t stream) {
    const float* q = (const float*)d_in[0];
    const float* k = (const float*)d_in[1];
    const float* v = (const float*)d_in[2];
    float* ctx = (float*)d_out;
    float* attn = ctx + (size_t)NB * SS * DD;

    unsigned short* kb = (unsigned short*)d_ws;            // B*S*D bf16
    unsigned short* vt = kb + (size_t)NB * SS * DD;        // [B][D][S] bf16

    prep_kernel<<<dim3(4, SS / 64, NB), 256, 0, stream>>>(k, v, kb, vt);
    attn_kernel<<<dim3((SS / TM) * NB), 512, 0, stream>>>(q, kb, vt, attn, ctx);
}